// Round 6
// baseline (973.515 us; speedup 1.0000x reference)
//
#include <hip/hip_runtime.h>

#define NN     50000
#define NRELB  20
#define RR     (2*NRELB + 1)      // 41
#define NHID   16
#define NCLASS 50
#define EB     1600000
#define WPB    4                  // waves per block (layer1)
#define NPB    8                  // nodes per block (layer2) = waves per block
#define RH     (RR * NHID)        // 656
#define NPBRH  (NPB * RH)         // 5248
#define STRIDE 128                // static CSR bucket size (max deg ~65+8*sigma << 128)

// Seed each node's bucket with its self-loop at slot 0.
__global__ void init_kernel(unsigned* __restrict__ cnt, unsigned* __restrict__ ekey) {
    int n = blockIdx.x * blockDim.x + threadIdx.x;
    if (n >= NN) return;
    cnt[n] = 1u;
    ekey[(size_t)n * STRIDE] = ((unsigned)(2 * NRELB) << 16) | (unsigned)n;
}

// One thread per base edge: emit forward + inverse into static buckets.
__global__ void scatter_kernel(const int* __restrict__ src, const int* __restrict__ rel,
                               const int* __restrict__ dst,
                               unsigned* __restrict__ cnt, unsigned* __restrict__ ekey) {
    int e = blockIdx.x * blockDim.x + threadIdx.x;
    if (e >= EB) return;
    int s = src[e], r = rel[e], o = dst[e];
    unsigned p1 = atomicAdd(&cnt[s], 1u);
    ekey[(size_t)s * STRIDE + p1] = ((unsigned)r << 16) | (unsigned)o;
    unsigned p2 = atomicAdd(&cnt[o], 1u);
    ekey[(size_t)o * STRIDE + p2] = ((unsigned)(r + NRELB) << 16) | (unsigned)s;
}

// Layer 1: one wave per node, h-major LDS [h*41+r], 2-deep pipelined edge loop.
__global__ __launch_bounds__(256) void layer1_kernel(
        const unsigned* __restrict__ ekey, const unsigned* __restrict__ cnt,
        const float* __restrict__ W1, const float* __restrict__ b1,
        float* __restrict__ h) {
    __shared__ float acc[WPB][RH];      // [h*41 + r]
    __shared__ float degL[WPB][RR];
    const int wave = threadIdx.x >> 6, lane = threadIdx.x & 63;
    const int n = blockIdx.x * WPB + wave;
    for (int i = lane; i < RH; i += 64) acc[wave][i] = 0.f;
    if (lane < RR) degL[wave][lane] = 0.f;
    __syncthreads();
    if (n < NN) {
        const int deg = cnt[n];
        const int g = lane >> 2, q = (lane & 3) * 4;
        const unsigned* ek = ekey + (size_t)n * STRIDE;
        for (int i = g; i < deg; i += 32) {
            unsigned k0 = ek[i];
            int r0 = k0 >> 16, o0 = k0 & 0xFFFF;
            float4 v0 = *(const float4*)(W1 + ((size_t)(r0 * NN + o0)) * NHID + q);
            const bool has1 = (i + 16) < deg;
            unsigned k1 = 0; float4 v1 = v0; int r1 = 0;
            if (has1) {
                k1 = ek[i + 16];
                r1 = k1 >> 16;
                v1 = *(const float4*)(W1 + ((size_t)(r1 * NN + (k1 & 0xFFFF))) * NHID + q);
            }
            atomicAdd(&acc[wave][(q + 0) * RR + r0], v0.x);
            atomicAdd(&acc[wave][(q + 1) * RR + r0], v0.y);
            atomicAdd(&acc[wave][(q + 2) * RR + r0], v0.z);
            atomicAdd(&acc[wave][(q + 3) * RR + r0], v0.w);
            if ((lane & 3) == 0) atomicAdd(&degL[wave][r0], 1.f);
            if (has1) {
                atomicAdd(&acc[wave][(q + 0) * RR + r1], v1.x);
                atomicAdd(&acc[wave][(q + 1) * RR + r1], v1.y);
                atomicAdd(&acc[wave][(q + 2) * RR + r1], v1.z);
                atomicAdd(&acc[wave][(q + 3) * RR + r1], v1.w);
                if ((lane & 3) == 0) atomicAdd(&degL[wave][r1], 1.f);
            }
        }
    }
    __syncthreads();
    if (lane < RR) {            // deg -> 1/deg in place
        float d = degL[wave][lane];
        degL[wave][lane] = (d != 0.f) ? 1.f / d : 0.f;
    }
    __syncthreads();
    if (n < NN) {
        const int g = lane >> 4, hh = lane & 15;
        float sum = 0.f;
        for (int r = g; r < RR; r += 4)
            sum += acc[wave][hh * RR + r] * degL[wave][r];
        sum += __shfl_xor(sum, 16);
        sum += __shfl_xor(sum, 32);
        if (lane < NHID) h[n * NHID + lane] = fmaxf(sum + b1[lane], 0.f);
    }
}

// Layer 2 + log-softmax. 512 threads, 8 waves, 1 node per wave.
__global__ __launch_bounds__(512) void layer2_kernel(
        const unsigned* __restrict__ ekey, const unsigned* __restrict__ cnt,
        const float* __restrict__ h, const float* __restrict__ W2,
        const float* __restrict__ b2, float* __restrict__ out) {
    __shared__ float buf[NPBRH];               // accA [nd][h*41+r] -> accT [rh][nd]
    __shared__ float degL[NPB * RR];           // counts -> 1/deg in place
    __shared__ float partial[NPB * NPB * NCLASS];   // [wave][nd][class]

    const int tid = threadIdx.x, wave = tid >> 6, lane = tid & 63;
    const int nbase = blockIdx.x * NPB;

    for (int i = tid; i < NPBRH; i += 512) buf[i] = 0.f;
    if (tid < NPB * RR) degL[tid] = 0.f;
    __syncthreads();

    // Phase A: accumulate sum of h[o] per (node, r, h); 2-deep pipelined.
    {
        const int nd = wave;
        const int n = nbase + nd;
        const int deg = cnt[n];
        const int g = lane >> 2, q = (lane & 3) * 4;
        const unsigned* ek = ekey + (size_t)n * STRIDE;
        float* base = &buf[nd * RH];
        for (int i = g; i < deg; i += 32) {
            unsigned k0 = ek[i];
            int r0 = k0 >> 16;
            float4 v0 = *(const float4*)(h + (k0 & 0xFFFF) * NHID + q);
            const bool has1 = (i + 16) < deg;
            unsigned k1 = 0; float4 v1 = v0; int r1 = 0;
            if (has1) {
                k1 = ek[i + 16];
                r1 = k1 >> 16;
                v1 = *(const float4*)(h + (k1 & 0xFFFF) * NHID + q);
            }
            atomicAdd(base + (q + 0) * RR + r0, v0.x);
            atomicAdd(base + (q + 1) * RR + r0, v0.y);
            atomicAdd(base + (q + 2) * RR + r0, v0.z);
            atomicAdd(base + (q + 3) * RR + r0, v0.w);
            if ((lane & 3) == 0) atomicAdd(&degL[nd * RR + r0], 1.f);
            if (has1) {
                atomicAdd(base + (q + 0) * RR + r1, v1.x);
                atomicAdd(base + (q + 1) * RR + r1, v1.y);
                atomicAdd(base + (q + 2) * RR + r1, v1.z);
                atomicAdd(base + (q + 3) * RR + r1, v1.w);
                if ((lane & 3) == 0) atomicAdd(&degL[nd * RR + r1], 1.f);
            }
        }
    }
    __syncthreads();
    if (tid < NPB * RR) {                      // deg -> 1/deg
        float d = degL[tid];
        degL[tid] = (d != 0.f) ? 1.f / d : 0.f;
    }
    __syncthreads();

    // Phase B: scale by 1/deg and transpose IN PLACE (register-staged).
    {
        float tmp[11];
        #pragma unroll
        for (int k = 0; k < 11; ++k) {
            int i = tid + (k << 9);
            if (i < NPBRH) {
                int rh = i >> 3, nd = i & 7;
                int r = rh >> 4, hh = rh & 15;
                tmp[k] = buf[nd * RH + hh * RR + r] * degL[nd * RR + r];
            }
        }
        __syncthreads();
        #pragma unroll
        for (int k = 0; k < 11; ++k) {
            int i = tid + (k << 9);
            if (i < NPBRH) buf[i] = tmp[k];
        }
    }
    __syncthreads();

    // Phase C: contraction. Wave w owns an rh eighth (82); lane = class (clamped).
    {
        const int c = (lane < NCLASS) ? lane : NCLASS - 1;
        float s[NPB];
        #pragma unroll
        for (int q = 0; q < NPB; ++q) s[q] = 0.f;
        const int rh0 = wave * (RH / NPB);          // 82 per wave
        #pragma unroll 2
        for (int j = 0; j < RH / NPB; ++j) {
            const int rh = rh0 + j;
            float4 a = *(const float4*)&buf[rh * NPB + 0];
            float4 b = *(const float4*)&buf[rh * NPB + 4];
            float w = W2[rh * NCLASS + c];
            s[0] += a.x * w; s[1] += a.y * w; s[2] += a.z * w; s[3] += a.w * w;
            s[4] += b.x * w; s[5] += b.y * w; s[6] += b.z * w; s[7] += b.w * w;
        }
        if (lane < NCLASS) {
            #pragma unroll
            for (int q = 0; q < NPB; ++q)
                partial[(wave * NPB + q) * NCLASS + lane] = s[q];
        }
    }
    __syncthreads();

    // Phase D: cross-wave reduce + log-softmax; each wave finishes 1 node.
    {
        const int nd = wave;
        const int n = nbase + nd;
        float x = -INFINITY;
        if (lane < NCLASS) {
            x = b2[lane];
            #pragma unroll
            for (int w = 0; w < NPB; ++w)
                x += partial[(w * NPB + nd) * NCLASS + lane];
        }
        float m = x;
        #pragma unroll
        for (int off = 32; off; off >>= 1) m = fmaxf(m, __shfl_xor(m, off));
        float ex = (lane < NCLASS) ? expf(x - m) : 0.f;
        float ss = ex;
        #pragma unroll
        for (int off = 32; off; off >>= 1) ss += __shfl_xor(ss, off);
        float ls = logf(ss) + m;
        if (lane < NCLASS) out[n * NCLASS + lane] = x - ls;
    }
}

extern "C" void kernel_launch(void* const* d_in, const int* in_sizes, int n_in,
                              void* d_out, int out_size, void* d_ws, size_t ws_size,
                              hipStream_t stream) {
    const int*   src = (const int*)d_in[0];
    const int*   rel = (const int*)d_in[1];
    const int*   dst = (const int*)d_in[2];
    const float* W1  = (const float*)d_in[3];
    const float* b1  = (const float*)d_in[4];
    const float* W2  = (const float*)d_in[5];
    const float* b2  = (const float*)d_in[6];
    float* out = (float*)d_out;

    unsigned* cnt  = (unsigned*)d_ws;                 // NN
    unsigned* ekey = cnt + NN;                        // NN * STRIDE (25.6 MB)
    float*    h    = (float*)(ekey + (size_t)NN * STRIDE);   // NN*NHID

    const int blk = 256;
    init_kernel<<<(NN + blk - 1) / blk, blk, 0, stream>>>(cnt, ekey);
    scatter_kernel<<<(EB + blk - 1) / blk, blk, 0, stream>>>(src, rel, dst, cnt, ekey);
    layer1_kernel<<<NN / WPB, blk, 0, stream>>>(ekey, cnt, W1, b1, h);
    layer2_kernel<<<NN / NPB, 512, 0, stream>>>(ekey, cnt, h, W2, b2, out);
}